// Round 9
// baseline (14693.196 us; speedup 1.0000x reference)
//
#include <hip/hip_runtime.h>
#include <hip/hip_bf16.h>

#define TT 2048
#define HH 1024
#define GH 4096

__device__ __forceinline__ float sigm(float x){ return 1.0f / (1.0f + __expf(-x)); }

// -------- Phase 1: plain fp32 tiled GEMM (validated r3-r8) --------
#define BM 128
#define BN 64
#define BK 32

__global__ __launch_bounds__(256) void gemm_simple(
    const int* __restrict__ tokens,
    const float* __restrict__ emb,
    const float* __restrict__ Wih,
    const float* __restrict__ bih,
    const float* __restrict__ bhh,
    float* __restrict__ gx)
{
  __shared__ float As[BM][BK+1];
  __shared__ float Bs[BN][BK+1];
  __shared__ int tok_s[BM];

  const int tid = threadIdx.x;
  const int bn = blockIdx.x;
  const int bm = blockIdx.y;
  const int m0 = bm*BM, n0 = bn*BN;

  if (tid < BM) tok_s[tid] = tokens[m0 + tid];
  __syncthreads();

  const int tm = tid >> 4;
  const int tn = tid & 15;

  float acc[8][4];
  #pragma unroll
  for (int i = 0; i < 8; ++i)
    #pragma unroll
    for (int j = 0; j < 4; ++j) acc[i][j] = 0.0f;

  for (int k0 = 0; k0 < HH; k0 += BK) {
    for (int idx = tid; idx < BM*BK; idx += 256) {
      int r = idx >> 5, c = idx & 31;
      As[r][c] = emb[(size_t)tok_s[r]*HH + k0 + c];
    }
    for (int idx = tid; idx < BN*BK; idx += 256) {
      int r = idx >> 5, c = idx & 31;
      Bs[r][c] = Wih[(size_t)(n0 + r)*HH + k0 + c];
    }
    __syncthreads();
    #pragma unroll
    for (int k = 0; k < BK; ++k) {
      float a[8], bb[4];
      #pragma unroll
      for (int i = 0; i < 8; ++i) a[i] = As[tm*8 + i][k];
      #pragma unroll
      for (int j = 0; j < 4; ++j) bb[j] = Bs[tn*4 + j][k];
      #pragma unroll
      for (int i = 0; i < 8; ++i)
        #pragma unroll
        for (int j = 0; j < 4; ++j)
          acc[i][j] = fmaf(a[i], bb[j], acc[i][j]);
    }
    __syncthreads();
  }

  float bias[4];
  #pragma unroll
  for (int j = 0; j < 4; ++j) {
    int col = n0 + tn*4 + j;
    bias[j] = bih[col] + bhh[col];
  }
  #pragma unroll
  for (int i = 0; i < 8; ++i) {
    int r = m0 + tm*8 + i;
    #pragma unroll
    for (int j = 0; j < 4; ++j)
      gx[(size_t)r*GH + (n0 + tn*4 + j)] = acc[i][j] + bias[j];
  }
}

// -------- Phase 2: persistent scan, listener-wave + pinned-register weights --------
// 128 blocks x 5 waves. Wave 0 polls all 1024 slots -> LDS double buffer.
// Waves 1..4 each own 2 outputs: in-register dot (w pinned via asm), folded
// butterfly reduce, act+publish by lanes 0/32. One __syncthreads per step.
#define GBLK 128
#define NTH 320

__global__ __launch_bounds__(NTH, 2) void lstm_scan(
    const float* __restrict__ gx,
    const float* __restrict__ Whh,
    unsigned long long* slots,     // [2][1024] {tag<<32 | fp32 h}
    float* __restrict__ out)       // [2048] fp32 = h ; c
{
  const int b   = blockIdx.x;
  const int tid = threadIdx.x;
  const int lane = tid & 63;
  const int wv   = tid >> 6;          // 0..4

  __shared__ float hbuf[2][1024];

  const bool isCompute = (wv >= 1);
  const int cwv = wv - 1;             // 0..3 for compute waves
  const int o0 = (b << 3) + (cwv << 1);
  const int o1 = o0 + 1;

  // w[r][j]: r = out_sel*4 + gate (r&3=gate, r>>2=out). Pinned in VGPRs.
  float w[8][16];
  if (isCompute) {
    #pragma unroll
    for (int r = 0; r < 8; ++r) {
      const int jrow = ((r & 3) << 10) + ((r >> 2) ? o1 : o0);
      const float* wr = Whh + (size_t)jrow * HH + lane;
      #pragma unroll
      for (int j = 0; j < 16; ++j)
        w[r][j] = wr[64 * j];
    }
    #pragma unroll
    for (int r = 0; r < 8; ++r)
      #pragma unroll
      for (int j = 0; j < 16; ++j)
        asm volatile("" : "+v"(w[r][j]));   // opaque def: forbid remat inside loop
  }

  const bool actlane = isCompute && ((lane == 0) || (lane == 32));
  const int myout = (lane == 0) ? o0 : o1;
  float cst = 0.0f;
  float g4[4] = {0.f, 0.f, 0.f, 0.f};
  if (actlane) {
    #pragma unroll
    for (int g = 0; g < 4; ++g) g4[g] = gx[(g << 10) + myout];   // t = 0
  }

  for (int i = tid; i < 1024; i += NTH) hbuf[0][i] = 0.0f;       // h(0) = 0
  __syncthreads();

  for (int t = 0; t < TT; ++t) {
    const int cur = t & 1, nxt = cur ^ 1;

    if (isCompute) {
      float ng[4] = {0.f, 0.f, 0.f, 0.f};
      if (actlane && t + 1 < TT) {
        #pragma unroll
        for (int g = 0; g < 4; ++g)           // prefetch next step's gx early
          ng[g] = gx[(size_t)(t+1)*GH + (g << 10) + myout];
      }

      float h[16];
      #pragma unroll
      for (int j = 0; j < 16; ++j) h[j] = hbuf[cur][64*j + lane];

      float acc[8];
      #pragma unroll
      for (int r = 0; r < 8; ++r) acc[r] = 0.0f;
      #pragma unroll
      for (int j = 0; j < 16; ++j) {
        const float hj = h[j];
        #pragma unroll
        for (int r = 0; r < 8; ++r) acc[r] = fmaf(w[r][j], hj, acc[r]);
      }

      // folded butterfly: lane l ends holding S_{l&7}
      float v4[4];
      #pragma unroll
      for (int i = 0; i < 4; ++i) {
        float a = (lane & 1) ? acc[2*i+1] : acc[2*i];
        float q = (lane & 1) ? acc[2*i]   : acc[2*i+1];
        v4[i] = a + __shfl_xor(q, 1);
      }
      float v2[2];
      #pragma unroll
      for (int i = 0; i < 2; ++i) {
        float a = (lane & 2) ? v4[2*i+1] : v4[2*i];
        float q = (lane & 2) ? v4[2*i]   : v4[2*i+1];
        v2[i] = a + __shfl_xor(q, 2);
      }
      float v1;
      {
        float a = (lane & 4) ? v2[1] : v2[0];
        float q = (lane & 4) ? v2[0] : v2[1];
        v1 = a + __shfl_xor(q, 4);
      }
      v1 += __shfl_xor(v1, 8);
      v1 += __shfl_xor(v1, 16);
      v1 += __shfl_xor(v1, 32);

      const int base = (lane >= 32) ? 4 : 0;
      float xi = __shfl(v1, base + 0);
      float xf = __shfl(v1, base + 1);
      float xg = __shfl(v1, base + 2);
      float xo = __shfl(v1, base + 3);

      if (actlane) {
        xi += g4[0]; xf += g4[1]; xg += g4[2]; xo += g4[3];
        cst = sigm(xf)*cst + sigm(xi)*tanhf(xg);
        float hnew = sigm(xo)*tanhf(cst);
        if (t == TT-1) {
          out[myout]        = hnew;
          out[1024 + myout] = cst;
        } else {
          unsigned long long* db = slots + (size_t)nxt * 1024;
          unsigned long long pv =
              (((unsigned long long)(unsigned)(t+1)) << 32) |
              (unsigned long long)__float_as_uint(hnew);
          __hip_atomic_store(&db[myout], pv, __ATOMIC_RELAXED, __HIP_MEMORY_SCOPE_AGENT);
          #pragma unroll
          for (int g = 0; g < 4; ++g) g4[g] = ng[g];
        }
      }
    } else {
      // listener wave: collect h(t+1) from all blocks into hbuf[nxt]
      if (t < TT-1) {
        const unsigned long long* sb = slots + (size_t)nxt * 1024;
        const unsigned tg = (unsigned)(t+1);
        unsigned long long v[16];
        #pragma unroll
        for (int j = 0; j < 16; ++j)
          v[j] = __hip_atomic_load(&sb[lane + 64*j], __ATOMIC_RELAXED, __HIP_MEMORY_SCOPE_AGENT);
        #pragma unroll
        for (int j = 0; j < 16; ++j)
          while ((unsigned)(v[j] >> 32) != tg)
            v[j] = __hip_atomic_load(&sb[lane + 64*j], __ATOMIC_RELAXED, __HIP_MEMORY_SCOPE_AGENT);
        #pragma unroll
        for (int j = 0; j < 16; ++j)
          hbuf[nxt][64*j + lane] = __uint_as_float((unsigned)v[j]);
      }
    }
    __syncthreads();
  }
}

// fallback: ws too small -> zeros
__global__ void zero_out(float* out){
  int i = blockIdx.x*256 + threadIdx.x;
  if (i < 2048) out[i] = 0.0f;
}

extern "C" void kernel_launch(void* const* d_in, const int* in_sizes, int n_in,
                              void* d_out, int out_size, void* d_ws, size_t ws_size,
                              hipStream_t stream) {
  (void)in_sizes; (void)n_in; (void)out_size;
  const int* tokens = (const int*)d_in[0];
  const float* emb  = (const float*)d_in[1];
  const float* Wih  = (const float*)d_in[2];
  const float* Whh  = (const float*)d_in[3];
  const float* bih  = (const float*)d_in[4];
  const float* bhh  = (const float*)d_in[5];
  float* out = (float*)d_out;

  // ws: [0,16K) slots[2][1024] u64 | [16K, ...) gx fp32 [2048][4096]
  unsigned long long* slots = (unsigned long long*)d_ws;
  float* gx = (float*)((char*)d_ws + 16384);
  const size_t needF32 = 16384 + (size_t)TT*GH*sizeof(float);

  hipMemsetAsync(slots, 0, 16384, stream);
  if (ws_size >= needF32) {
    gemm_simple<<<dim3(64,16), dim3(256), 0, stream>>>(tokens, emb, Wih, bih, bhh, gx);
    lstm_scan<<<dim3(GBLK), dim3(NTH), 0, stream>>>(gx, Whh, slots, out);
  } else {
    zero_out<<<dim3(8), dim3(256), 0, stream>>>(out);
  }
}